// Round 9
// baseline (303.919 us; speedup 1.0000x reference)
//
#include <hip/hip_runtime.h>
#include <stdint.h>

// Problem constants (match reference)
#define NP 32    // num networks (P)
#define NH 128   // hidden (H)
#define NB 32    // batch (B)
#define NT 256   // time (T)
#define FH 512   // 4*H

typedef __attribute__((ext_vector_type(4))) float float4_t;
typedef __attribute__((ext_vector_type(8))) __bf16 bf16x8;

static __device__ __forceinline__ float4_t mfma_bf16(bf16x8 a, bf16x8 b, float4_t c) {
  return __builtin_amdgcn_mfma_f32_16x16x32_bf16(a, b, c, 0, 0, 0);
}

#define LOG2E 1.4426950408889634f

// Raw workgroup barrier: drains LDS ops only (cross-wave h visibility), does
// NOT drain vmcnt — pending global loads/stores stay in flight across it.
#define BAR() __asm__ volatile("s_waitcnt lgkmcnt(0)\n\ts_barrier" ::: "memory")

// R9: FAT waves — halve the CU-level DS burst.
// Updated step model (R8 post-mortem): DS pipe is CU-shared; reads/CU =
// waves/CU x 4 ds_read_b128 (~12 cyc each) regardless of wave width. 8 thin
// waves = 32 reads ~ 400 cyc bursted post-barrier. 4 fat waves = 16 reads
// ~ 200 cyc; MFMA/trans/VALU per SIMD unchanged (1 wave x 2x work = 2 waves
// x 1x). Cost: 1 wave/SIMD exposes chain latency (~300 cyc) — a good trade
// per the model. (R4's fat-wave failure carried 4x per-wave work on 64 CUs;
// not comparable.)
// SESSION RULES: no DS-pipe/cross-lane ops in loop (R5); no global loads on
// the lgkm chain (R3); no deep dependent MFMA chains (R6); loop-invariant
// C-roots (bias4/z4) so no per-step accumulator zero-init.
//
// Grid: 256 blocks = 32 nets x 8 batch-groups (M=4 real batches).
// Block: 256 thr = 4 waves; wave w owns units [32w,32w+32) = 2 unit-tiles
// x 4 gates = 8 N-tiles, 40 MFMA/wave/step.
// Dup trick (R8): A rows hold batch l16&3 -> C reg r = batch r; lane adopts
// reg index = quad via v_cndmask. 2 (batch,unit) pairs per lane -> 20 trans.
__global__ __launch_bounds__(256, 1) void clstm_fused(
    const float* __restrict__ X, const float* __restrict__ Wih,
    const float* __restrict__ Whh, const float* __restrict__ bih,
    const float* __restrict__ bhh, const float* __restrict__ Wout,
    const float* __restrict__ bout, float* __restrict__ out)
{
  const int net = blockIdx.x >> 3, bq = blockIdx.x & 7;
  const int tid = threadIdx.x;
  const int w = tid >> 6, lane = tid & 63;
  const int quad = lane >> 4, l16 = lane & 15;

  // h A-fragments, double buffered, 4 DISTINCT rows: [buf][kc][kquad][m<4][j]
  __shared__ __bf16 hfrag[2][4][4][4][8];   // 2 KB total

  { // zero BOTH buffers (h0 = 0): 2KB = 512 ints, 2 per thread
    ((int*)hfrag)[2*tid] = 0; ((int*)hfrag)[2*tid+1] = 0;
  }
  __syncthreads();  // once, outside the loop

  // ---- load weights into register B-fragments (one-time) ----
  // B-frag layout for 16x16x32: lane holds B[k = quad*8 + j][n = l16].
  // ut in {0,1}: unit u = 32w + 16ut + l16; gate col = g*128 + u.
  bf16x8 bfrag[2][4][5];
  float4_t bias4[2][4];
#pragma unroll
  for (int ut = 0; ut < 2; ++ut) {
#pragma unroll
    for (int g = 0; g < 4; ++g) {
      const float scale = (g == 2) ? (-2.0f*LOG2E) : (-LOG2E);
      const int col = g*NH + 32*w + 16*ut + l16;
#pragma unroll
      for (int kc = 0; kc < 5; ++kc) {
        const float* src = (kc == 0) ? (Wih + ((size_t)net*FH + col)*NP + quad*8)
                                     : (Whh + ((size_t)net*FH + col)*NH + (kc-1)*32 + quad*8);
        bf16x8 bf;
#pragma unroll
        for (int j = 0; j < 8; ++j) bf[j] = (__bf16)(src[j] * scale);
        bfrag[ut][g][kc] = bf;
      }
      const float b = (bih[net*FH + col] + bhh[net*FH + col]) * scale;
      bias4[ut][g] = (float4_t){b, b, b, b};
    }
  }

  // head B-frags: B[k][n] = wout[k] broadcast over all 16 cols n.
  bf16x8 wof[4];
#pragma unroll
  for (int kc = 0; kc < 4; ++kc) {
    const float* wp = Wout + net*NH + kc*32 + quad*8;
#pragma unroll
    for (int j = 0; j < 8; ++j) wof[kc][j] = (__bf16)wp[j];
  }
  const float bo = bout[net];
  const float4_t bo4 = {bo, bo, bo, bo};
  const float4_t z4  = {0.f, 0.f, 0.f, 0.f};   // loop-invariant C-root

  // c state, PRE-SCALED by -2log2e; one per (batch=quad, unit-tile)
  float cs0 = 0.f, cs1 = 0.f;
  const float S2 = -2.0f*LOG2E;

  // x A-frag source: row l16 -> batch bq*4 + (l16&3) (4x dup)
  const float* xrow = X + (size_t)(bq*4 + (l16 & 3))*(NT*NP) + quad*8;

  // h write coords: unit u = 32w + 16ut + l16 -> kc = w, kquad = 2ut+(l16>>3),
  // j = l16&7, row = quad (this lane's batch).
  const int q2lo = l16 >> 3, jj = l16 & 7;

  // head store base: out[(bq*4 + r)*NT*NP + t*NP + net], stored by wave 0
  // lane 0 (quad 0 C rows 0..3 = batches 0..3).
  float* outp = out + ((size_t)bq*4)*(NT*NP) + net;

  // preload + convert x for t=0; xp then walks t=1..NT-1
  bf16x8 ax;
  {
    float xv0[8];
    *(float4_t*)&xv0[0] = *(const float4_t*)xrow;
    *(float4_t*)&xv0[4] = *(const float4_t*)(xrow + 4);
#pragma unroll
    for (int j = 0; j < 8; ++j) ax[j] = (__bf16)xv0[j];
  }
  const float* xp = xrow + NP;
  float xv[8] = {0.f,0.f,0.f,0.f,0.f,0.f,0.f,0.f};

  for (int t = 0; t < NT; ++t) {
    const int rd = t & 1, wr = rd ^ 1;

    // ---- 1. h A-frags (row = l16&3; 4-lane same-address broadcast) ----
    bf16x8 ah[4];
#pragma unroll
    for (int kc = 0; kc < 4; ++kc)
      ah[kc] = *(const bf16x8*)&hfrag[rd][kc][quad][l16 & 3][0];

    // ---- 2. x-MFMAs first: no LDS dependence, fills ds_read latency ----
    // C-root = bias4 (loop-invariant regs; D != C so no re-init needed).
    float4_t accx[2][4];
#pragma unroll
    for (int ut = 0; ut < 2; ++ut)
#pragma unroll
      for (int g = 0; g < 4; ++g)
        accx[ut][g] = mfma_bf16(ax, bfrag[ut][g][0], bias4[ut][g]);

    // ---- 3. x prefetch for t+1 (scalar-guarded, pointer-incremented) ----
    if (t + 1 < NT) {
      *(float4_t*)&xv[0] = *(const float4_t*)xp;
      *(float4_t*)&xv[4] = *(const float4_t*)(xp + 4);
    }

    // ---- 4. h-MFMAs: 8 tiles x two parallel chains (depth 2); 16
    // independent chains interleave on the matrix pipe ----
    float4_t acc[2][4];
#pragma unroll
    for (int ut = 0; ut < 2; ++ut) {
#pragma unroll
      for (int g = 0; g < 4; ++g) {
        float4_t a0 = mfma_bf16(ah[0], bfrag[ut][g][1], accx[ut][g]);
        float4_t a1 = mfma_bf16(ah[2], bfrag[ut][g][3], z4);
        a0 = mfma_bf16(ah[1], bfrag[ut][g][2], a0);
        a1 = mfma_bf16(ah[3], bfrag[ut][g][4], a1);
        acc[ut][g] = a0 + a1;
      }
    }

    // ---- 5. select lane's batch (= quad) via cndmask; 2 pairs/lane ----
    float gv0[4], gv1[4];
#pragma unroll
    for (int g = 0; g < 4; ++g) {
      float a01 = (quad & 1) ? acc[0][g][1] : acc[0][g][0];
      float a23 = (quad & 1) ? acc[0][g][3] : acc[0][g][2];
      gv0[g] = (quad & 2) ? a23 : a01;
      float b01 = (quad & 1) ? acc[1][g][1] : acc[1][g][0];
      float b23 = (quad & 1) ? acc[1][g][3] : acc[1][g][2];
      gv1[g] = (quad & 2) ? b23 : b01;
    }

    // ---- 6. activations + state update: two interleavable chains ----
    float h0, h1;
    {
      float ei = __builtin_amdgcn_exp2f(gv0[0]);
      float ig = __builtin_amdgcn_rcpf(1.0f + ei);
      float ef = __builtin_amdgcn_exp2f(gv0[1]);
      float fg = __builtin_amdgcn_rcpf(1.0f + ef);
      float eg = __builtin_amdgcn_exp2f(fminf(gv0[2], 126.0f));
      float rg = __builtin_amdgcn_rcpf(1.0f + eg);
      float t0 = S2 * rg;
      float gg2 = t0 - t0 * eg;                               // tanh(g)*S2
      float eo = __builtin_amdgcn_exp2f(gv0[3]);
      float og = __builtin_amdgcn_rcpf(1.0f + eo);
      cs0 = fg * cs0 + ig * gg2;                              // c * S2
      float ec = __builtin_amdgcn_exp2f(fminf(cs0, 126.0f));
      float rc = __builtin_amdgcn_rcpf(1.0f + ec);
      h0 = og * (rc - ec * rc);                               // og*tanh(c)
    }
    {
      float ei = __builtin_amdgcn_exp2f(gv1[0]);
      float ig = __builtin_amdgcn_rcpf(1.0f + ei);
      float ef = __builtin_amdgcn_exp2f(gv1[1]);
      float fg = __builtin_amdgcn_rcpf(1.0f + ef);
      float eg = __builtin_amdgcn_exp2f(fminf(gv1[2], 126.0f));
      float rg = __builtin_amdgcn_rcpf(1.0f + eg);
      float t0 = S2 * rg;
      float gg2 = t0 - t0 * eg;
      float eo = __builtin_amdgcn_exp2f(gv1[3]);
      float og = __builtin_amdgcn_rcpf(1.0f + eo);
      cs1 = fg * cs1 + ig * gg2;
      float ec = __builtin_amdgcn_exp2f(fminf(cs1, 126.0f));
      float rc = __builtin_amdgcn_rcpf(1.0f + ec);
      h1 = og * (rc - ec * rc);
    }

    // ---- 7. write h' (bf16): 2 ds_write_b16, row = quad ----
    hfrag[wr][w][q2lo    ][quad][jj] = (__bf16)h0;
    hfrag[wr][w][q2lo + 2][quad][jj] = (__bf16)h1;

    // ---- 8. fused head (wave 0; ah = h_{t-1} -> out[t-1]) ----
    if (w == 0 && t > 0) {
      float4_t p0 = mfma_bf16(ah[0], wof[0], bo4);
      float4_t p1 = mfma_bf16(ah[2], wof[2], z4);
      p0 = mfma_bf16(ah[1], wof[1], p0);
      p1 = mfma_bf16(ah[3], wof[3], p1);
      float4_t po = p0 + p1;
      if (lane == 0) {
#pragma unroll
        for (int r = 0; r < 4; ++r)
          outp[(size_t)r*(NT*NP) + (t - 1)*NP] = po[r];
      }
    }

    // ---- 9. convert next x; advance pointer ----
#pragma unroll
    for (int j = 0; j < 8; ++j) ax[j] = (__bf16)xv[j];
    xp += NP;

    BAR();  // lgkmcnt-only barrier
  }

  // ---- epilogue: head for t = NT-1 (h_{NT-1} is in hfrag[NT&1]) ----
  if (w == 0) {
    bf16x8 ahf[4];
#pragma unroll
    for (int kc = 0; kc < 4; ++kc)
      ahf[kc] = *(const bf16x8*)&hfrag[NT & 1][kc][quad][l16 & 3][0];
    float4_t p0 = mfma_bf16(ahf[0], wof[0], bo4);
    float4_t p1 = mfma_bf16(ahf[2], wof[2], z4);
    p0 = mfma_bf16(ahf[1], wof[1], p0);
    p1 = mfma_bf16(ahf[3], wof[3], p1);
    float4_t po = p0 + p1;
    if (lane == 0) {
#pragma unroll
      for (int r = 0; r < 4; ++r)
        outp[(size_t)r*(NT*NP) + (NT - 1)*NP] = po[r];
    }
  }
}

extern "C" void kernel_launch(void* const* d_in, const int* in_sizes, int n_in,
                              void* d_out, int out_size, void* d_ws, size_t ws_size,
                              hipStream_t stream) {
  const float* X    = (const float*)d_in[0];
  const float* Wih  = (const float*)d_in[1];
  const float* Whh  = (const float*)d_in[2];
  const float* bih  = (const float*)d_in[3];
  const float* bhh  = (const float*)d_in[4];
  const float* Wout = (const float*)d_in[5];
  const float* bout = (const float*)d_in[6];
  float* out = (float*)d_out;
  (void)in_sizes; (void)n_in; (void)out_size; (void)d_ws; (void)ws_size;

  clstm_fused<<<256, 256, 0, stream>>>(X, Wih, Whh, bih, bhh, Wout, bout, out);
}